// Round 14
// baseline (11178.999 us; speedup 1.0000x reference)
//
#include <hip/hip_runtime.h>
#include <hip/hip_bf16.h>

#define N_TOT 3840
#define B_SZ  128
#define K_REC 1792
#define T_STEPS 200
#define HWREG_XCC_ID_IMM 6164   // id=20, offset=0, size=4
#define RING 8
#define A_PLANE 28672    // u16 per (slot,rg) A plane: 16 rows * 1792
#define DS_PLANE 32768   // f32 per (slot,rg) ds plane: 2 br * 16 rows * 1024
#define NBLK 240

typedef __attribute__((ext_vector_type(8))) short short8;
typedef __attribute__((ext_vector_type(4))) float f32x4;
typedef unsigned long long u64;

__device__ __forceinline__ unsigned short f2bf(float f) {
    __hip_bfloat16 h = __float2bfloat16(f);
    return *reinterpret_cast<unsigned short*>(&h);
}
__device__ __forceinline__ float bf2f(unsigned short u) {
    __hip_bfloat16 h = *reinterpret_cast<__hip_bfloat16*>(&u);
    return __bfloat162float(h);
}

// ---- prep: W_aug^T in MFMA-fragment order: [tile240][kc58][lane64][e8], hi/lo ----
__global__ void prep_w(const float* __restrict__ w_rec, const float* __restrict__ w_in,
                       const float* __restrict__ mask,
                       unsigned short* __restrict__ Wfh, unsigned short* __restrict__ Wfl) {
    int n = blockIdx.x * 256 + threadIdx.x;
    int k = blockIdx.y;
    if (n >= N_TOT) return;
    float v;
    if (k < K_REC) {
        int region = (k >= 896) ? 1 : 0;
        int kk = k - 896 * region;
        int i = 1920 * region + (kk < 512 ? kk : 1024 + kk);
        v = fabsf(w_rec[(size_t)i * N_TOT + n]) * mask[(size_t)i * N_TOT + n];
    } else {
        v = w_in[(size_t)(k - K_REC) * N_TOT + n];
    }
    unsigned short hb = f2bf(v);
    unsigned short lb = f2bf(v - bf2f(hb));
    int nt = n >> 4;
    int l  = ((k >> 3) & 3) * 16 + (n & 15);
    int kc = k >> 5, e = k & 7;
    size_t off = ((size_t)(nt * 58 + kc) * 64 + l) * 8 + e;
    Wfh[off] = hb;
    Wfl[off] = lb;
}

// ---- prep: x -> per-(t,rg) A-fragment tail (kc 56,57), hi/lo ----
__global__ void prep_xf(const float* __restrict__ x,
                        unsigned short* __restrict__ xfh, unsigned short* __restrict__ xfl) {
    int idx = blockIdx.x * 256 + threadIdx.x;   // 200*8*1024
    if (idx >= 1638400) return;
    int t = idx >> 13;
    int rem = idx & 8191;
    int rg = rem >> 10;
    int s = rem & 1023;
    int kc2 = s >> 9, ln = (s >> 3) & 63, e = s & 7;
    int row = ln & 15;
    int k2 = kc2 * 32 + (ln >> 4) * 8 + e;
    float f = x[((size_t)t * B_SZ + 16 * rg + row) * 64 + k2];
    unsigned short hb = f2bf(f);
    xfh[idx] = hb;
    xfl[idx] = f2bf(f - bf2f(hb));
}

// ---- init ring slot 0 from h0: A row-major [rg][row16][k1792] hi/lo, ds [rg][br][row][1024] ----
__global__ void init_state(const float* __restrict__ h0,
                           unsigned short* __restrict__ rAh, unsigned short* __restrict__ rAl,
                           float* __restrict__ dsR) {
    int n = blockIdx.x * 256 + threadIdx.x;
    int b = blockIdx.y;
    if (n >= N_TOT) return;
    float hv = h0[(size_t)b * N_TOT + n];
    int rg = b >> 4, row = b & 15;
    int region = (n >= 1920) ? 1 : 0;
    int nn = n - 1920 * region;
    bool dend = (nn >= 512 && nn < 1536);
    float r = dend ? tanhf(hv) : fmaxf(hv, 0.f);
    if (!dend) {
        int kcol = 896 * region + (nn < 512 ? nn : nn - 1024);
        unsigned short hb = f2bf(r);
        size_t off = (size_t)rg * A_PLANE + row * K_REC + kcol;
        rAh[off] = hb;
        rAl[off] = f2bf(r - bf2f(hb));
    } else {
        int d = nn - 512;
        int br = d >> 9;
        int c = region * 512 + (d & 511);
        dsR[(size_t)rg * DS_PLANE + br * 16384 + row * 1024 + c] = r;
    }
}

__global__ void zero_bar(int* __restrict__ bar) {
    for (int i = threadIdx.x; i < 8448; i += 1024) bar[i] = 0;
}

// ---- final readout: out[t][rg*16+row][o] = sum over (cg<4, m<8) partials ----
__global__ void reduce_out(const float* __restrict__ part, float* __restrict__ out) {
    int t = blockIdx.x;
    for (int j = threadIdx.x; j < 1280; j += 256) {
        int rg = j / 160, rem = j % 160;
        int row = rem / 10, o = rem % 10;
        float s = 0.f;
        #pragma unroll
        for (int q = 0; q < 32; ++q) {
            int cg = q >> 3, m = q & 7;
            s += part[(size_t)(((t * 8 + rg) * 4 + cg) * 8 + m) * 160 + row * 10 + o];
        }
        out[(size_t)t * 1280 + j] = s;
    }
}

// bar ints: [G*16] arrive | [4096+G*16] release | [8192+x] claims | [8256+x*16] inv flags
// ---- persistent kernel: block = 16 batch rows x 128 cols. A (114KB) staged to LDS,
//      shared by 16 waves; W read per-wave from L2 (static, XCD-clustered, ~3.6MB).
//      Fabric/step: 7.3MB A + noise (was 220MB). Ring+inv, sweep barrier: proven. ----
__global__ void __launch_bounds__(1024, 4)
rnn_persist(const unsigned short* __restrict__ Wfh, const unsigned short* __restrict__ Wfl,
            unsigned short* __restrict__ rAh, unsigned short* __restrict__ rAl,
            float* __restrict__ dsR,
            const unsigned short* __restrict__ xfh, const unsigned short* __restrict__ xfl,
            const float* __restrict__ noise, const float* __restrict__ bias,
            const float* __restrict__ w_out, const float* __restrict__ h0,
            float* __restrict__ part, int* __restrict__ bar) {
    __shared__ unsigned short Ah_s[29696];   // 58 kc * 64 lane * 8 e
    __shared__ unsigned short Al_s[29696];
    __shared__ f32x4 red_s[8 * 64];
    __shared__ int xcc_s, slot_s;

    const int tid  = threadIdx.x;
    const int lane = tid & 63;
    const int wv   = tid >> 6;            // 0..15
    const int m    = wv & 7;              // col sub-tile (16 cols)
    const int kh   = wv >> 3;             // k-half 0/1
    const int l15  = lane & 15, g = lane >> 4;

    // claim a slot on this physical XCD; 2 spare blocks per XCD exit
    if (tid == 0) {
        int xcc = __builtin_amdgcn_s_getreg(HWREG_XCC_ID_IMM) & 7;
        xcc_s = xcc;
        slot_s = __hip_atomic_fetch_add(&bar[8192 + xcc], 1,
                                        __ATOMIC_RELAXED, __HIP_MEMORY_SCOPE_AGENT);
    }
    __syncthreads();
    const int xcc = xcc_s;
    const int s   = slot_s;
    if (s >= 30) return;
    const int G  = xcc * 30 + s;          // 0..239
    const int rg = G & 7;                 // batch row-group (rows rg*16..+15)
    const int cg = G >> 3;                // col-group (cols cg*128..+127)
    const bool leader = (s == 0);

    // per-wave column facts (whole block is category-pure: boundaries at 128-multiples)
    const int n      = cg * 128 + m * 16 + l15;
    const int region = (n >= 1920) ? 1 : 0;
    const int nn     = n - 1920 * region;
    const bool es    = (nn < 512);
    const bool dend  = (nn >= 512 && nn < 1536);
    const int kcol   = 896 * region + (nn < 512 ? nn : nn - 1024);
    const int dd     = nn - 512;
    const int dbr    = (dd >> 9) & 1;
    const int dcol   = region * 512 + (dd & 511);
    const int esc    = region * 512 + nn;
    const float bias_v = bias[n];
    const bool is_read = (!region) && es;     // cg 0..3
    float wo[10];
    #pragma unroll
    for (int o = 0; o < 10; ++o) wo[o] = is_read ? w_out[n * 10 + o] : 0.f;
    const float nsc = sqrtf(0.4f) * 0.01f;

    // W tile for (cg, m): global fragment-order, L2-resident (static)
    const unsigned short* Wh_t = Wfh + (size_t)(cg * 8 + m) * 58 * 512;
    const unsigned short* Wl_t = Wfl + (size_t)(cg * 8 + m) * 58 * 512;
    const int kbase = kh * 28;

    // h block-private in registers (kh0 waves)
    float hreg[4];
    if (!kh) {
        #pragma unroll
        for (int i = 0; i < 4; ++i)
            hreg[i] = h0[(size_t)(rg * 16 + g * 4 + i) * N_TOT + n];
    }

    for (int t = 0; t < T_STEPS; ++t) {
        const int sc = t & (RING - 1);
        const int sn = (t + 1) & (RING - 1);
        const unsigned short* rcH = rAh + (size_t)(sc * 8 + rg) * A_PLANE;
        const unsigned short* rcL = rAl + (size_t)(sc * 8 + rg) * A_PLANE;
        unsigned short* rnH = rAh + (size_t)(sn * 8 + rg) * A_PLANE;
        unsigned short* rnL = rAl + (size_t)(sn * 8 + rg) * A_PLANE;
        const float* dsc = dsR + (size_t)(sc * 8 + rg) * DS_PLANE;
        float* dsn = dsR + (size_t)(sn * 8 + rg) * DS_PLANE;

        // ---- stage A (16 rows, full K) global->LDS in fragment order ----
        for (int ch = tid; ch < 3712; ch += 1024) {
            int kc = ch >> 6, ln = ch & 63;
            short8 vh, vl;
            if (kc < 56) {
                size_t off = (size_t)(ln & 15) * K_REC + kc * 32 + (ln >> 4) * 8;
                vh = *reinterpret_cast<const short8*>(rcH + off);
                vl = *reinterpret_cast<const short8*>(rcL + off);
            } else {
                size_t off = ((size_t)t * 8 + rg) * 1024 + (kc - 56) * 512 + ln * 8;
                vh = *reinterpret_cast<const short8*>(xfh + off);
                vl = *reinterpret_cast<const short8*>(xfl + off);
            }
            *reinterpret_cast<short8*>(Ah_s + ch * 8) = vh;
            *reinterpret_cast<short8*>(Al_s + ch * 8) = vl;
        }
        __syncthreads();

        // early loads (consumed in epilogue; overlap with GEMM)
        float nz[4], dsv0[4], dsv1[4];
        if (!kh) {
            #pragma unroll
            for (int i = 0; i < 4; ++i) {
                int row = g * 4 + i;
                nz[i] = noise[((size_t)t * B_SZ + rg * 16 + row) * N_TOT + n];
                dsv0[i] = es ? dsc[row * 1024 + esc] : 0.f;
                dsv1[i] = es ? dsc[16384 + row * 1024 + esc] : 0.f;
            }
        }

        // ---- GEMM: A from LDS (shared), W from L2 via 3-deep register ring ----
        f32x4 acc = {0.f, 0.f, 0.f, 0.f};
        short8 pwh[3], pwl[3];
        #pragma unroll
        for (int j = 0; j < 3; ++j) {
            pwh[j] = *reinterpret_cast<const short8*>(Wh_t + (kbase + j) * 512 + lane * 8);
            pwl[j] = *reinterpret_cast<const short8*>(Wl_t + (kbase + j) * 512 + lane * 8);
        }
        #pragma unroll
        for (int kc = 0; kc < 28; ++kc) {
            short8 cwh = pwh[kc % 3], cwl = pwl[kc % 3];
            if (kc < 25) {
                pwh[kc % 3] = *reinterpret_cast<const short8*>(Wh_t + (kbase + kc + 3) * 512 + lane * 8);
                pwl[kc % 3] = *reinterpret_cast<const short8*>(Wl_t + (kbase + kc + 3) * 512 + lane * 8);
            }
            int ka = kbase + kc;
            short8 avh = *reinterpret_cast<const short8*>(Ah_s + (ka * 64 + lane) * 8);
            short8 avl = *reinterpret_cast<const short8*>(Al_s + (ka * 64 + lane) * 8);
            acc = __builtin_amdgcn_mfma_f32_16x16x32_bf16(avh, cwh, acc, 0, 0, 0);
            acc = __builtin_amdgcn_mfma_f32_16x16x32_bf16(avh, cwl, acc, 0, 0, 0);
            acc = __builtin_amdgcn_mfma_f32_16x16x32_bf16(avl, cwh, acc, 0, 0, 0);
        }
        if (kh) {
            #pragma unroll
            for (int c = 0; c < 2; ++c) {
                short8 bvh = *reinterpret_cast<const short8*>(Wh_t + (56 + c) * 512 + lane * 8);
                short8 bvl = *reinterpret_cast<const short8*>(Wl_t + (56 + c) * 512 + lane * 8);
                short8 avh = *reinterpret_cast<const short8*>(Ah_s + ((56 + c) * 64 + lane) * 8);
                short8 avl = *reinterpret_cast<const short8*>(Al_s + ((56 + c) * 64 + lane) * 8);
                acc = __builtin_amdgcn_mfma_f32_16x16x32_bf16(avh, bvh, acc, 0, 0, 0);
                acc = __builtin_amdgcn_mfma_f32_16x16x32_bf16(avh, bvl, acc, 0, 0, 0);
                acc = __builtin_amdgcn_mfma_f32_16x16x32_bf16(avl, bvh, acc, 0, 0, 0);
            }
            red_s[m * 64 + lane] = acc;
        }
        __syncthreads();

        // ---- epilogue (kh0): combine halves, update state, write r/ds/readout ----
        if (!kh) {
            f32x4 o4 = red_s[m * 64 + lane];
            acc[0] += o4[0]; acc[1] += o4[1]; acc[2] += o4[2]; acc[3] += o4[3];
            #pragma unroll
            for (int i = 0; i < 4; ++i) {
                int row = g * 4 + i;
                float tot = acc[i] + bias_v;
                if (es) tot += dsv0[i] + dsv1[i];
                float hn = 0.8f * hreg[i] + 0.2f * tot + nsc * nz[i];
                hreg[i] = hn;
                float r = dend ? tanhf(hn) : fmaxf(hn, 0.f);
                if (!dend) {
                    // adjacent l15 own adjacent kcol: paired u32 sc1 stores
                    unsigned int hv32 = f2bf(r);
                    unsigned int lv32 = f2bf(r - bf2f((unsigned short)hv32));
                    unsigned int hp = (unsigned int)__shfl_xor((int)hv32, 1);
                    unsigned int lp = (unsigned int)__shfl_xor((int)lv32, 1);
                    if (!(l15 & 1)) {
                        __hip_atomic_store((unsigned int*)(rnH + row * K_REC + kcol),
                                           hv32 | (hp << 16),
                                           __ATOMIC_RELAXED, __HIP_MEMORY_SCOPE_AGENT);
                        __hip_atomic_store((unsigned int*)(rnL + row * K_REC + kcol),
                                           lv32 | (lp << 16),
                                           __ATOMIC_RELAXED, __HIP_MEMORY_SCOPE_AGENT);
                    }
                } else {
                    unsigned int rb = __float_as_uint(r);
                    unsigned int rp = (unsigned int)__shfl_xor((int)rb, 1);
                    if (!(l15 & 1)) {
                        float* dst = dsn + dbr * 16384 + row * 1024 + dcol;
                        u64 w = (u64)rb | ((u64)rp << 32);
                        __hip_atomic_store((u64*)dst, w,
                                           __ATOMIC_RELAXED, __HIP_MEMORY_SCOPE_AGENT);
                    }
                }
                if (is_read) {
                    #pragma unroll
                    for (int o = 0; o < 10; ++o) {
                        float pp = r * wo[o];
                        pp += __shfl_xor(pp, 1);
                        pp += __shfl_xor(pp, 2);
                        pp += __shfl_xor(pp, 4);
                        pp += __shfl_xor(pp, 8);
                        if (l15 == 0)
                            __hip_atomic_store(&part[(size_t)(((t * 8 + rg) * 4 + cg) * 8 + m) * 160
                                                     + row * 10 + o],
                                               pp, __ATOMIC_RELAXED, __HIP_MEMORY_SCOPE_AGENT);
                    }
                }
            }
        }

        // ---- RMW-free sweep barrier (r12) + leader inv every 8 steps (r11) ----
        if (t != T_STEPS - 1) {
            const int e1 = t + 1;
            __syncthreads();    // drains all sc1 stores (vmcnt 0) before arrive
            if (tid == 0)
                __hip_atomic_store(&bar[G * 16], e1,
                                   __ATOMIC_RELAXED, __HIP_MEMORY_SCOPE_AGENT);
            if (G == NBLK - 1 && wv == 0) {
                for (;;) {
                    bool ok = true;
                    #pragma unroll
                    for (int j = 0; j < 4; ++j) {
                        int idx = j * 64 + lane;
                        if (idx < NBLK) {
                            int v = __hip_atomic_load(&bar[idx * 16], __ATOMIC_RELAXED,
                                                      __HIP_MEMORY_SCOPE_AGENT);
                            ok = ok && (v >= e1);
                        }
                    }
                    if (__all(ok)) break;
                    __builtin_amdgcn_s_sleep(1);
                }
                #pragma unroll
                for (int j = 0; j < 4; ++j) {
                    int idx = j * 64 + lane;
                    if (idx < NBLK)
                        __hip_atomic_store(&bar[4096 + idx * 16], e1,
                                           __ATOMIC_RELAXED, __HIP_MEMORY_SCOPE_AGENT);
                }
            }
            if (tid == 0) {
                while (__hip_atomic_load(&bar[4096 + G * 16], __ATOMIC_RELAXED,
                                         __HIP_MEMORY_SCOPE_AGENT) < e1)
                    __builtin_amdgcn_s_sleep(1);
                if ((t & (RING - 1)) == RING - 1) {
                    if (leader) {
                        __builtin_amdgcn_fence(__ATOMIC_ACQUIRE, "agent");  // 1 inv / 8 steps / XCD
                        __hip_atomic_store(&bar[8256 + xcc * 16], e1,
                                           __ATOMIC_RELAXED, __HIP_MEMORY_SCOPE_AGENT);
                    }
                    while (__hip_atomic_load(&bar[8256 + xcc * 16], __ATOMIC_RELAXED,
                                             __HIP_MEMORY_SCOPE_AGENT) < e1)
                        __builtin_amdgcn_s_sleep(1);
                }
                asm volatile("" ::: "memory");
            }
            __syncthreads();
        }
    }
}

extern "C" void kernel_launch(void* const* d_in, const int* in_sizes, int n_in,
                              void* d_out, int out_size, void* d_ws, size_t ws_size,
                              hipStream_t stream) {
    const float* x     = (const float*)d_in[0];
    const float* noise = (const float*)d_in[1];
    const float* w_rec = (const float*)d_in[2];
    const float* w_in  = (const float*)d_in[3];
    const float* w_out = (const float*)d_in[4];
    const float* bias  = (const float*)d_in[5];
    const float* h0    = (const float*)d_in[6];
    const float* mask  = (const float*)d_in[7];
    float* out = (float*)d_out;

    char* ws = (char*)d_ws;
    unsigned short* Wfh = (unsigned short*)(ws + 0);           // 14,254,080 B
    unsigned short* Wfl = (unsigned short*)(ws + 14254080);
    unsigned short* rAh = (unsigned short*)(ws + 28508160);    // 8 slots x 8 rg x 57,344 B
    unsigned short* rAl = (unsigned short*)(ws + 32178176);
    float* dsR = (float*)(ws + 35848192);                      // 8 x 8 x 131,072 B
    unsigned short* xfh = (unsigned short*)(ws + 44236800);    // 3,276,800 B
    unsigned short* xfl = (unsigned short*)(ws + 47513600);
    int*   bar  = (int*)(ws + 50790400);                       // 33,792 B
    float* part = (float*)(ws + 50824192);                     // 32,768,000 B

    hipLaunchKernelGGL(prep_w, dim3(15, 1856), dim3(256), 0, stream, w_rec, w_in, mask, Wfh, Wfl);
    hipLaunchKernelGGL(prep_xf, dim3(6400), dim3(256), 0, stream, x, xfh, xfl);
    hipLaunchKernelGGL(init_state, dim3(15, B_SZ), dim3(256), 0, stream, h0, rAh, rAl, dsR);
    hipLaunchKernelGGL(zero_bar, dim3(1), dim3(1024), 0, stream, bar);

    void* params[] = {
        (void*)&Wfh, (void*)&Wfl, (void*)&rAh, (void*)&rAl, (void*)&dsR,
        (void*)&xfh, (void*)&xfl, (void*)&noise, (void*)&bias, (void*)&w_out,
        (void*)&h0, (void*)&part, (void*)&bar
    };
    hipLaunchCooperativeKernel(rnn_persist, dim3(256), dim3(1024), params, 0, stream);

    hipLaunchKernelGGL(reduce_out, dim3(T_STEPS), dim3(256), 0, stream, part, out);
}

// Round 15
// 10367.581 us; speedup vs baseline: 1.0783x; 1.0783x over previous
//
#include <hip/hip_runtime.h>
#include <hip/hip_bf16.h>

#define N_TOT 3840
#define B_SZ  128
#define K_REC 1792
#define T_STEPS 200
#define HWREG_XCC_ID_IMM 6164   // id=20, offset=0, size=4
#define RING 8
#define RST_SLOT 458752  // u16 per rSt slot: 128 rows * 112 kblocks * 32
#define DS_SLOT 262144   // f32 per ds slot (A half at 0, B half at 131072)
#define NBLK 240

typedef __attribute__((ext_vector_type(8))) short short8;
typedef __attribute__((ext_vector_type(4))) float f32x4;
typedef unsigned long long u64;

__device__ __forceinline__ unsigned short f2bf(float f) {
    __hip_bfloat16 h = __float2bfloat16(f);
    return *reinterpret_cast<unsigned short*>(&h);
}
__device__ __forceinline__ float bf2f(unsigned short u) {
    __hip_bfloat16 h = *reinterpret_cast<__hip_bfloat16*>(&u);
    return __bfloat162float(h);
}

// ---- prep: W_aug^T in MFMA-fragment order: [tile240][kc58][lane64][e8], hi/lo ----
__global__ void prep_w(const float* __restrict__ w_rec, const float* __restrict__ w_in,
                       const float* __restrict__ mask,
                       unsigned short* __restrict__ Wfh, unsigned short* __restrict__ Wfl) {
    int n = blockIdx.x * 256 + threadIdx.x;
    int k = blockIdx.y;
    if (n >= N_TOT) return;
    float v;
    if (k < K_REC) {
        int region = (k >= 896) ? 1 : 0;
        int kk = k - 896 * region;
        int i = 1920 * region + (kk < 512 ? kk : 1024 + kk);
        v = fabsf(w_rec[(size_t)i * N_TOT + n]) * mask[(size_t)i * N_TOT + n];
    } else {
        v = w_in[(size_t)(k - K_REC) * N_TOT + n];
    }
    unsigned short hb = f2bf(v);
    unsigned short lb = f2bf(v - bf2f(hb));
    int nt = n >> 4;
    int l  = ((k >> 3) & 3) * 16 + (n & 15);
    int kc = k >> 5, e = k & 7;
    size_t off = ((size_t)(nt * 58 + kc) * 64 + l) * 8 + e;
    Wfh[off] = hb;
    Wfl[off] = lb;
}

// ---- prep: x -> bf16 hi/lo (flat [t][b][64]) ----
__global__ void prep_x(const float* __restrict__ x,
                       unsigned short* __restrict__ xh, unsigned short* __restrict__ xl) {
    int i = blockIdx.x * 256 + threadIdx.x;
    if (i >= T_STEPS * B_SZ * 64) return;
    float f = x[i];
    unsigned short hb = f2bf(f);
    xh[i] = hb;
    xl[i] = f2bf(f - bf2f(hb));
}

// ---- init ring slot 0 from h0: rSt layout [b][112][hi16|lo16] ----
__global__ void init_state(const float* __restrict__ h0,
                           unsigned short* __restrict__ rSt, float* __restrict__ dsR) {
    int n = blockIdx.x * 256 + threadIdx.x;
    int b = blockIdx.y;
    if (n >= N_TOT) return;
    float hv = h0[(size_t)b * N_TOT + n];
    int region = (n >= 1920) ? 1 : 0;
    int nn = n - 1920 * region;
    bool dend = (nn >= 512 && nn < 1536);
    float r = dend ? tanhf(hv) : fmaxf(hv, 0.f);
    if (!dend) {
        int kcol = 896 * region + (nn < 512 ? nn : nn - 1024);
        unsigned short hb = f2bf(r);
        size_t off = ((size_t)b * 112 + (kcol >> 4)) * 32 + (kcol & 15);
        rSt[off]      = hb;
        rSt[off + 16] = f2bf(r - bf2f(hb));
    } else {
        int d = nn - 512;
        int br = d >> 9;
        int c = region * 512 + (d & 511);
        dsR[br * 131072 + b * 1024 + c] = r;
    }
}

__global__ void zero_bar(int* __restrict__ bar) {
    for (int i = threadIdx.x; i < 8448; i += 1024) bar[i] = 0;
}

// ---- final readout reduction ----
__global__ void reduce_out(const float* __restrict__ part, float* __restrict__ out) {
    int t = blockIdx.x;
    for (int j = threadIdx.x; j < 1280; j += 256) {
        float s = 0.f;
        #pragma unroll
        for (int q = 0; q < 32; ++q) s += part[(size_t)t * 40960 + q * 1280 + j];
        out[(size_t)t * 1280 + j] = s;
    }
}

// bar ints: [G*16] arrive | [4096+G*16] release | [8192+x] claims | [8256+x*16] inv flags
// ---- persistent kernel: 240 live blocks = 120 col-blocks (32 cols; W-hi x2 tiles in
//      LDS) x 2 row-halves (64 batch rows). A-broadcast volume HALVED: 110MB/step.
//      W-lo from L2 (static -> stale-safe). Ring+inv (r11), sweep barrier (r12). ----
__global__ void __launch_bounds__(1024, 4)
rnn_persist(const unsigned short* __restrict__ Wfh, const unsigned short* __restrict__ Wfl,
            unsigned short* __restrict__ rSt, float* __restrict__ dsR,
            const unsigned short* __restrict__ xh, const unsigned short* __restrict__ xl,
            const float* __restrict__ noise, const float* __restrict__ bias,
            const float* __restrict__ w_out, const float* __restrict__ h0,
            float* __restrict__ part, int* __restrict__ bar) {
    __shared__ unsigned short Wh_s[59392];   // 2 tiles x 58kc x 64lane x 8e (W-hi only)
    __shared__ f32x4 red_s[8 * 64];
    __shared__ int xcc_s, slot_s;

    const int tid  = threadIdx.x;
    const int lane = tid & 63;
    const int wv   = tid >> 6;            // 0..15
    const int m    = wv & 3;              // row sub-tile (16 rows)
    const int ct   = (wv >> 2) & 1;       // col sub-tile (16 cols)
    const int kh   = wv >> 3;             // k-half 0/1
    const int l15  = lane & 15, g = lane >> 4;

    // claim a slot on this physical XCD; 2 spare blocks per XCD exit (r14-proven)
    if (tid == 0) {
        int xcc = __builtin_amdgcn_s_getreg(HWREG_XCC_ID_IMM) & 7;
        xcc_s = xcc;
        slot_s = __hip_atomic_fetch_add(&bar[8192 + xcc], 1,
                                        __ATOMIC_RELAXED, __HIP_MEMORY_SCOPE_AGENT);
    }
    __syncthreads();
    const int xcc = xcc_s;
    const int s   = slot_s;
    if (s >= 30) return;
    const int G     = xcc * 30 + s;       // 0..239
    const int cb    = xcc * 15 + (s >> 1); // col-block 0..119 (XCD-clustered)
    const int rh    = s & 1;               // row-half
    const int rbase = rh * 64;
    const bool leader = (s == 0);

    // one-time: W-hi for this block's 2 col-tiles -> LDS (contiguous in Wfh)
    {
        const uint4* src = (const uint4*)(Wfh + (size_t)(cb * 2) * 29696);
        uint4* dst = (uint4*)Wh_s;
        for (int i = tid; i < 7424; i += 1024) dst[i] = src[i];
    }
    __syncthreads();

    // per-wave column facts (32-col block is category-pure; 16-col tile purer still)
    const int n      = cb * 32 + ct * 16 + l15;
    const int region = (n >= 1920) ? 1 : 0;
    const int nn     = n - 1920 * region;
    const bool es    = (nn < 512);
    const bool dend  = (nn >= 512 && nn < 1536);
    const int kcol   = 896 * region + (nn < 512 ? nn : nn - 1024);
    const int KB     = kcol >> 4;
    const int dd     = nn - 512;
    const int dbr    = (dd >> 9) & 1;
    const int dcol   = region * 512 + (dd & 511);
    const int esc    = region * 512 + nn;
    const float bias_v = bias[n];
    const bool is_read = (!region) && es;           // cb 0..15
    const int nt_part  = cb * 2 + ct;               // 0..31 for readout tiles
    float wo[10];
    #pragma unroll
    for (int o = 0; o < 10; ++o) wo[o] = is_read ? w_out[n * 10 + o] : 0.f;
    const float nsc = sqrtf(0.4f) * 0.01f;

    const unsigned short* Wl_t = Wfl + (size_t)(cb * 2 + ct) * 29696;  // W-lo: L2, static
    const int bA    = rbase + m * 16 + l15;          // A row for this lane
    const int kbase = kh * 28;
    const int gofs  = (g >> 1) * 32 + (g & 1) * 8;   // u16 offset within kblock pair

    // h block-private in registers (kh0 waves)
    float hreg[4];
    if (!kh) {
        #pragma unroll
        for (int i = 0; i < 4; ++i)
            hreg[i] = h0[(size_t)(rbase + m * 16 + g * 4 + i) * N_TOT + n];
    }

    // prologue prefetch for t=0 (pure inputs)
    float nz[4];
    short8 xvh[2], xvl[2];
    if (!kh) {
        #pragma unroll
        for (int i = 0; i < 4; ++i)
            nz[i] = noise[(size_t)(rbase + m * 16 + g * 4 + i) * N_TOT + n];
    } else {
        const unsigned short* xH = xh + (size_t)bA * 64 + g * 8;
        const unsigned short* xL = xl + (size_t)bA * 64 + g * 8;
        #pragma unroll
        for (int c = 0; c < 2; ++c) {
            xvh[c] = *reinterpret_cast<const short8*>(xH + c * 32);
            xvl[c] = *reinterpret_cast<const short8*>(xL + c * 32);
        }
    }

    for (int t = 0; t < T_STEPS; ++t) {
        const int sc = t & (RING - 1);
        const int sn = (t + 1) & (RING - 1);
        const unsigned short* rc = rSt + (size_t)sc * RST_SLOT;
        unsigned short* rn = rSt + (size_t)sn * RST_SLOT;
        const float* dsAc = dsR + (size_t)sc * DS_SLOT;
        const float* dsBc = dsAc + 131072;
        float* dsAn = dsR + (size_t)sn * DS_SLOT;
        float* dsBn = dsAn + 131072;

        float dsv0[4], dsv1[4];
        if (!kh) {
            #pragma unroll
            for (int i = 0; i < 4; ++i) {
                int b = rbase + m * 16 + g * 4 + i;
                dsv0[i] = es ? dsAc[b * 1024 + esc] : 0.f;
                dsv1[i] = es ? dsBc[b * 1024 + esc] : 0.f;
            }
        }

        // A-fragment base: hi at aB + kc*64, lo at +16 (same 64B line)
        const unsigned short* aB = rc + (size_t)bA * 3584 + (size_t)kbase * 64 + gofs;

        // GEMM: A hi/lo + W-lo via 3-deep rings (plain cached), W-hi from LDS
        f32x4 acc = {0.f, 0.f, 0.f, 0.f};
        short8 pah[3], pal[3], pwl[3];
        #pragma unroll
        for (int j = 0; j < 3; ++j) {
            pah[j] = *reinterpret_cast<const short8*>(aB + j * 64);
            pal[j] = *reinterpret_cast<const short8*>(aB + j * 64 + 16);
            pwl[j] = *reinterpret_cast<const short8*>(Wl_t + (kbase + j) * 512 + lane * 8);
        }
        #pragma unroll
        for (int kc = 0; kc < 28; ++kc) {
            short8 cah = pah[kc % 3], cal = pal[kc % 3], cwl = pwl[kc % 3];
            if (kc < 25) {
                pah[kc % 3] = *reinterpret_cast<const short8*>(aB + (kc + 3) * 64);
                pal[kc % 3] = *reinterpret_cast<const short8*>(aB + (kc + 3) * 64 + 16);
                pwl[kc % 3] = *reinterpret_cast<const short8*>(Wl_t + (kbase + kc + 3) * 512 + lane * 8);
            }
            int ka = kbase + kc;
            short8 cwh = *reinterpret_cast<const short8*>(Wh_s + ct * 29696 + (ka * 64 + lane) * 8);
            acc = __builtin_amdgcn_mfma_f32_16x16x32_bf16(cah, cwh, acc, 0, 0, 0);
            acc = __builtin_amdgcn_mfma_f32_16x16x32_bf16(cah, cwl, acc, 0, 0, 0);
            acc = __builtin_amdgcn_mfma_f32_16x16x32_bf16(cal, cwh, acc, 0, 0, 0);
        }
        if (kh) {
            #pragma unroll
            for (int c = 0; c < 2; ++c) {
                short8 bvh = *reinterpret_cast<const short8*>(Wh_s + ct * 29696 + ((56 + c) * 64 + lane) * 8);
                short8 bvl = *reinterpret_cast<const short8*>(Wl_t + (56 + c) * 512 + lane * 8);
                acc = __builtin_amdgcn_mfma_f32_16x16x32_bf16(xvh[c], bvh, acc, 0, 0, 0);
                acc = __builtin_amdgcn_mfma_f32_16x16x32_bf16(xvh[c], bvl, acc, 0, 0, 0);
                acc = __builtin_amdgcn_mfma_f32_16x16x32_bf16(xvl[c], bvh, acc, 0, 0, 0);
            }
            red_s[(ct * 4 + m) * 64 + lane] = acc;   // publish k-half partial
        }
        __syncthreads();

        if (!kh) {
            f32x4 o4 = red_s[(ct * 4 + m) * 64 + lane];
            acc[0] += o4[0]; acc[1] += o4[1]; acc[2] += o4[2]; acc[3] += o4[3];
            #pragma unroll
            for (int i = 0; i < 4; ++i) {
                int b = rbase + m * 16 + g * 4 + i;
                float tot = acc[i] + bias_v;
                if (es) tot += dsv0[i] + dsv1[i];
                float hn = 0.8f * hreg[i] + 0.2f * tot + nsc * nz[i];
                hreg[i] = hn;
                float r = dend ? tanhf(hn) : fmaxf(hn, 0.f);
                if (!dend) {
                    // adjacent l15 own adjacent kcol: paired u32 sc1 stores (hi, lo)
                    unsigned int hv32 = f2bf(r);
                    unsigned int lv32 = f2bf(r - bf2f((unsigned short)hv32));
                    unsigned int hp = (unsigned int)__shfl_xor((int)hv32, 1);
                    unsigned int lp = (unsigned int)__shfl_xor((int)lv32, 1);
                    if (!(l15 & 1)) {
                        unsigned short* dst = rn + ((size_t)b * 112 + KB) * 32 + (kcol & 15);
                        __hip_atomic_store((unsigned int*)dst, hv32 | (hp << 16),
                                           __ATOMIC_RELAXED, __HIP_MEMORY_SCOPE_AGENT);
                        __hip_atomic_store((unsigned int*)(dst + 16), lv32 | (lp << 16),
                                           __ATOMIC_RELAXED, __HIP_MEMORY_SCOPE_AGENT);
                    }
                } else {
                    unsigned int rb = __float_as_uint(r);
                    unsigned int rp = (unsigned int)__shfl_xor((int)rb, 1);
                    if (!(l15 & 1)) {
                        float* dst = (dbr ? dsBn : dsAn) + b * 1024 + dcol;
                        u64 w = (u64)rb | ((u64)rp << 32);
                        __hip_atomic_store((u64*)dst, w,
                                           __ATOMIC_RELAXED, __HIP_MEMORY_SCOPE_AGENT);
                    }
                }
                if (is_read) {
                    #pragma unroll
                    for (int o = 0; o < 10; ++o) {
                        float pp = r * wo[o];
                        pp += __shfl_xor(pp, 1);
                        pp += __shfl_xor(pp, 2);
                        pp += __shfl_xor(pp, 4);
                        pp += __shfl_xor(pp, 8);
                        if (l15 == 0)
                            __hip_atomic_store(&part[(size_t)t * 40960 + nt_part * 1280 + b * 10 + o],
                                               pp, __ATOMIC_RELAXED, __HIP_MEMORY_SCOPE_AGENT);
                    }
                }
            }
        }

        if (t != T_STEPS - 1) {
            const int e1 = t + 1;
            // prefetch pure inputs for t+1 before the barrier
            if (!kh) {
                const float* noise_nx = noise + (size_t)(t + 1) * B_SZ * N_TOT;
                #pragma unroll
                for (int i = 0; i < 4; ++i)
                    nz[i] = noise_nx[(size_t)(rbase + m * 16 + g * 4 + i) * N_TOT + n];
            } else {
                const unsigned short* xH = xh + ((size_t)(t + 1) * B_SZ + bA) * 64 + g * 8;
                const unsigned short* xL = xl + ((size_t)(t + 1) * B_SZ + bA) * 64 + g * 8;
                #pragma unroll
                for (int c = 0; c < 2; ++c) {
                    xvh[c] = *reinterpret_cast<const short8*>(xH + c * 32);
                    xvl[c] = *reinterpret_cast<const short8*>(xL + c * 32);
                }
            }

            // ---- RMW-free sweep barrier (r12) + leader inv every 8 steps (r11) ----
            __syncthreads();    // drains all sc1 stores (vmcnt 0) before arrive
            if (tid == 0)
                __hip_atomic_store(&bar[G * 16], e1,
                                   __ATOMIC_RELAXED, __HIP_MEMORY_SCOPE_AGENT);
            if (G == NBLK - 1 && wv == 0) {
                for (;;) {
                    bool ok = true;
                    #pragma unroll
                    for (int j = 0; j < 4; ++j) {
                        int idx = j * 64 + lane;
                        if (idx < NBLK) {
                            int v = __hip_atomic_load(&bar[idx * 16], __ATOMIC_RELAXED,
                                                      __HIP_MEMORY_SCOPE_AGENT);
                            ok = ok && (v >= e1);
                        }
                    }
                    if (__all(ok)) break;
                    __builtin_amdgcn_s_sleep(1);
                }
                #pragma unroll
                for (int j = 0; j < 4; ++j) {
                    int idx = j * 64 + lane;
                    if (idx < NBLK)
                        __hip_atomic_store(&bar[4096 + idx * 16], e1,
                                           __ATOMIC_RELAXED, __HIP_MEMORY_SCOPE_AGENT);
                }
            }
            if (tid == 0) {
                while (__hip_atomic_load(&bar[4096 + G * 16], __ATOMIC_RELAXED,
                                         __HIP_MEMORY_SCOPE_AGENT) < e1)
                    __builtin_amdgcn_s_sleep(1);
                if ((t & (RING - 1)) == RING - 1) {
                    if (leader) {
                        __builtin_amdgcn_fence(__ATOMIC_ACQUIRE, "agent");  // 1 inv / 8 steps / XCD
                        __hip_atomic_store(&bar[8256 + xcc * 16], e1,
                                           __ATOMIC_RELAXED, __HIP_MEMORY_SCOPE_AGENT);
                    }
                    while (__hip_atomic_load(&bar[8256 + xcc * 16], __ATOMIC_RELAXED,
                                             __HIP_MEMORY_SCOPE_AGENT) < e1)
                        __builtin_amdgcn_s_sleep(1);
                }
                asm volatile("" ::: "memory");
            }
            __syncthreads();
        }
    }
}

extern "C" void kernel_launch(void* const* d_in, const int* in_sizes, int n_in,
                              void* d_out, int out_size, void* d_ws, size_t ws_size,
                              hipStream_t stream) {
    const float* x     = (const float*)d_in[0];
    const float* noise = (const float*)d_in[1];
    const float* w_rec = (const float*)d_in[2];
    const float* w_in  = (const float*)d_in[3];
    const float* w_out = (const float*)d_in[4];
    const float* bias  = (const float*)d_in[5];
    const float* h0    = (const float*)d_in[6];
    const float* mask  = (const float*)d_in[7];
    float* out = (float*)d_out;

    char* ws = (char*)d_ws;
    unsigned short* Wfh = (unsigned short*)(ws + 0);
    unsigned short* Wfl = (unsigned short*)(ws + 14254080);
    unsigned short* rSt = (unsigned short*)(ws + 28508160);   // 8 x 917504 B
    float* dsR = (float*)(ws + 35848192);                     // 8 x 1048576 B
    unsigned short* xh = (unsigned short*)(ws + 44236800);
    unsigned short* xl = (unsigned short*)(ws + 47513600);
    int*   bar  = (int*)(ws + 50790400);                      // 33792 B
    float* part = (float*)(ws + 50824192);                    // 32.77 MB

    hipLaunchKernelGGL(prep_w, dim3(15, 1856), dim3(256), 0, stream, w_rec, w_in, mask, Wfh, Wfl);
    hipLaunchKernelGGL(prep_x, dim3(6400), dim3(256), 0, stream, x, xh, xl);
    hipLaunchKernelGGL(init_state, dim3(15, B_SZ), dim3(256), 0, stream, h0, rSt, dsR);
    hipLaunchKernelGGL(zero_bar, dim3(1), dim3(1024), 0, stream, bar);

    void* params[] = {
        (void*)&Wfh, (void*)&Wfl, (void*)&rSt, (void*)&dsR,
        (void*)&xh, (void*)&xl, (void*)&noise, (void*)&bias, (void*)&w_out,
        (void*)&h0, (void*)&part, (void*)&bar
    };
    hipLaunchCooperativeKernel(rnn_persist, dim3(256), dim3(1024), params, 0, stream);

    hipLaunchKernelGGL(reduce_out, dim3(T_STEPS), dim3(256), 0, stream, part, out);
}

// Round 16
// 3536.914 us; speedup vs baseline: 3.1607x; 2.9313x over previous
//
#include <hip/hip_runtime.h>
#include <hip/hip_bf16.h>

#define N_TOT 3840
#define B_SZ  128
#define K_REC 1792
#define T_STEPS 200
#define NTILES 240
#define LDS_HALF 29696   // u16 per W half-tile: 58 kc * 64 lanes * 8 elems
#define HWREG_XCC_ID_IMM 6164   // id=20, offset=0, size=4
#define RING 8
#define RFR_SLOT 475136  // u16 per state slot: 8 m * 58 kc * 1024 (hi 512 | lo 512)
#define DS_SLOT 262144   // f32 per ds slot (A half at 0, B half at 131072)
#define ROOT_NT 239

typedef __attribute__((ext_vector_type(8))) short short8;
typedef __attribute__((ext_vector_type(4))) float f32x4;
typedef unsigned long long u64;

__device__ __forceinline__ unsigned short f2bf(float f) {
    __hip_bfloat16 h = __float2bfloat16(f);
    return *reinterpret_cast<unsigned short*>(&h);
}
__device__ __forceinline__ float bf2f(unsigned short u) {
    __hip_bfloat16 h = *reinterpret_cast<__hip_bfloat16*>(&u);
    return __bfloat162float(h);
}
__device__ __forceinline__ void st16_sc1(void* p, short8 v) {
    asm volatile("global_store_dwordx4 %0, %1, off sc1" :: "v"(p), "v"(v) : "memory");
}
__device__ __forceinline__ void st16f_sc1(void* p, f32x4 v) {
    asm volatile("global_store_dwordx4 %0, %1, off sc1" :: "v"(p), "v"(v) : "memory");
}

// ---- prep: W_aug^T in MFMA-fragment order: [tile240][kc58][lane64][e8], hi/lo ----
__global__ void prep_w(const float* __restrict__ w_rec, const float* __restrict__ w_in,
                       const float* __restrict__ mask,
                       unsigned short* __restrict__ Wfh, unsigned short* __restrict__ Wfl) {
    int n = blockIdx.x * 256 + threadIdx.x;
    int k = blockIdx.y;
    if (n >= N_TOT) return;
    float v;
    if (k < K_REC) {
        int region = (k >= 896) ? 1 : 0;
        int kk = k - 896 * region;
        int i = 1920 * region + (kk < 512 ? kk : 1024 + kk);
        v = fabsf(w_rec[(size_t)i * N_TOT + n]) * mask[(size_t)i * N_TOT + n];
    } else {
        v = w_in[(size_t)(k - K_REC) * N_TOT + n];
    }
    unsigned short hb = f2bf(v);
    unsigned short lb = f2bf(v - bf2f(hb));
    int nt = n >> 4;
    int l  = ((k >> 3) & 3) * 16 + (n & 15);
    int kc = k >> 5, e = k & 7;
    size_t off = ((size_t)(nt * 58 + kc) * 64 + l) * 8 + e;
    Wfh[off] = hb;
    Wfl[off] = lb;
}

// ---- prep: x -> fragment chunks xF[t][m][c][hi 512 u16 | lo 512 u16] ----
__global__ void prep_xf(const float* __restrict__ x, unsigned short* __restrict__ xF) {
    int idx = blockIdx.x * 256 + threadIdx.x;   // 200*8*2*512
    if (idx >= 1638400) return;
    int t = idx >> 13;
    int rem = idx & 8191;
    int m = rem >> 10;
    int s = rem & 1023;
    int c = s >> 9, w = s & 511;
    int ln = w >> 3, e = w & 7;
    int row = ln & 15;
    int k2 = c * 32 + ((ln >> 4) & 3) * 8 + e;
    float f = x[((size_t)t * B_SZ + m * 16 + row) * 64 + k2];
    unsigned short hb = f2bf(f);
    size_t base = ((size_t)(t * 8 + m) * 2 + c) * 1024 + w;
    xF[base]       = hb;
    xF[base + 512] = f2bf(f - bf2f(hb));
}

// ---- init ring slot 0 from h0: fragment layout [m][kc][hi512|lo512] + ds row-major ----
__global__ void init_state(const float* __restrict__ h0,
                           unsigned short* __restrict__ rFr, float* __restrict__ dsR) {
    int n = blockIdx.x * 256 + threadIdx.x;
    int b = blockIdx.y;
    if (n >= N_TOT) return;
    float hv = h0[(size_t)b * N_TOT + n];
    int region = (n >= 1920) ? 1 : 0;
    int nn = n - 1920 * region;
    bool dend = (nn >= 512 && nn < 1536);
    float r = dend ? tanhf(hv) : fmaxf(hv, 0.f);
    if (!dend) {
        int kcol = 896 * region + (nn < 512 ? nn : nn - 1024);
        int m = b >> 4;
        int kc = kcol >> 5;
        int ln = (b & 15) | (((kcol >> 3) & 3) << 4);
        unsigned short hb = f2bf(r);
        size_t off = ((size_t)(m * 58 + kc)) * 1024 + ln * 8 + (kcol & 7);
        rFr[off]       = hb;
        rFr[off + 512] = f2bf(r - bf2f(hb));
    } else {
        int d = nn - 512;
        int br = d >> 9;
        int c = region * 512 + (d & 511);
        dsR[br * 131072 + b * 1024 + c] = r;
    }
}

__global__ void zero_bar(int* __restrict__ bar) {
    for (int i = threadIdx.x; i < 8448; i += 1024) bar[i] = 0;
}

// ---- final readout reduction ----
__global__ void reduce_out(const float* __restrict__ part, float* __restrict__ out) {
    int t = blockIdx.x;
    for (int j = threadIdx.x; j < 1280; j += 256) {
        float s = 0.f;
        #pragma unroll
        for (int q = 0; q < 32; ++q) s += part[(size_t)t * 40960 + q * 1280 + j];
        out[(size_t)t * 1280 + j] = s;
    }
}

// bar ints: [G*16] arrive | [4096+G*16] release | [8192+x] claims | [8256+x*16] inv flags
// ---- persistent kernel: W in LDS; A-state in MFMA-FRAGMENT ORDER (1KB coalesced
//      chunk loads, 1 lookup/line, 6-deep ring); ring+inv (r11); sweep barrier (r12) ----
__global__ void __launch_bounds__(1024, 4)
rnn_persist(const unsigned short* __restrict__ Wfh, const unsigned short* __restrict__ Wfl,
            unsigned short* __restrict__ rFr, float* __restrict__ dsR,
            const unsigned short* __restrict__ xF,
            const float* __restrict__ noise, const float* __restrict__ bias,
            const float* __restrict__ w_out, const float* __restrict__ h0,
            float* __restrict__ part, int* __restrict__ bar) {
    __shared__ unsigned short Wh_s[LDS_HALF];
    __shared__ unsigned short Wl_s[LDS_HALF];
    __shared__ f32x4 red_s[8 * 64];      // also per-wave 1KB transpose scratch
    __shared__ int xcc_s, lead_s;
    char* scratch = (char*)red_s;

    const int nt   = blockIdx.x;
    const int tid  = threadIdx.x;
    const int lane = tid & 63;
    const int wv   = tid >> 6;
    const int m    = wv & 7;             // row-group (batch rows m*16..+15)
    const int kh   = wv >> 3;            // k-half
    const int l15  = lane & 15, g = lane >> 4;

    if (tid == 0) {
        int xcc = __builtin_amdgcn_s_getreg(HWREG_XCC_ID_IMM) & 7;
        xcc_s = xcc;
        lead_s = (__hip_atomic_fetch_add(&bar[8192 + xcc], 1,
                                         __ATOMIC_RELAXED, __HIP_MEMORY_SCOPE_AGENT) == 0);
    }

    {   // one-time: W tile -> LDS
        const uint4* s0 = (const uint4*)(Wfh + (size_t)nt * LDS_HALF);
        const uint4* s1 = (const uint4*)(Wfl + (size_t)nt * LDS_HALF);
        uint4* d0 = (uint4*)Wh_s;
        uint4* d1 = (uint4*)Wl_s;
        for (int i = tid; i < LDS_HALF / 8; i += 1024) { d0[i] = s0[i]; d1[i] = s1[i]; }
    }
    __syncthreads();
    const int  xcc    = xcc_s;
    const bool leader = (lead_s != 0);

    const int n      = nt * 16 + l15;
    const int region = (n >= 1920) ? 1 : 0;
    const int nn     = n - 1920 * region;
    const bool es    = (nn < 512);
    const bool dend  = (nn >= 512 && nn < 1536);
    const int kcol   = 896 * region + (nn < 512 ? nn : nn - 1024);
    const int KB     = (kcol - l15) >> 4;            // block's kblock (uniform)
    const int dd     = nn - 512;
    const int dbr    = (dd >> 9) & 1;
    const int dcol   = region * 512 + (dd & 511);
    const int dcol0  = dcol - l15;
    const int esc    = region * 512 + nn;
    const float bias_v = bias[n];
    const bool is_read = (!region) && es;
    float wo[10];
    #pragma unroll
    for (int o = 0; o < 10; ++o) wo[o] = is_read ? w_out[n * 10 + o] : 0.f;
    const float nsc = sqrtf(0.4f) * 0.01f;

    const int kbase = kh * 28;

    // h block-private in registers (kh0 waves)
    float hreg[4];
    if (!kh) {
        #pragma unroll
        for (int i = 0; i < 4; ++i)
            hreg[i] = h0[(size_t)(m * 16 + g * 4 + i) * N_TOT + n];
    }

    // prologue prefetch for t=0 (pure inputs)
    float nz[4];
    short8 xvh[2], xvl[2];
    if (!kh) {
        #pragma unroll
        for (int i = 0; i < 4; ++i)
            nz[i] = noise[(size_t)(m * 16 + g * 4 + i) * N_TOT + n];
    } else {
        const unsigned short* xb = xF + ((size_t)m * 2) * 1024 + lane * 8;
        xvh[0] = *reinterpret_cast<const short8*>(xb);
        xvl[0] = *reinterpret_cast<const short8*>(xb + 512);
        xvh[1] = *reinterpret_cast<const short8*>(xb + 1024);
        xvl[1] = *reinterpret_cast<const short8*>(xb + 1536);
    }

    for (int t = 0; t < T_STEPS; ++t) {
        const int sc = t & (RING - 1);
        const int sn = (t + 1) & (RING - 1);
        const unsigned short* rc = rFr + (size_t)sc * RFR_SLOT;
        unsigned short* rn = rFr + (size_t)sn * RFR_SLOT;
        const float* dsAc = dsR + (size_t)sc * DS_SLOT;
        const float* dsBc = dsAc + 131072;
        float* dsAn = dsR + (size_t)sn * DS_SLOT;
        float* dsBn = dsAn + 131072;

        float dsv0[4], dsv1[4];
        if (!kh) {
            #pragma unroll
            for (int i = 0; i < 4; ++i) {
                int b = m * 16 + g * 4 + i;
                dsv0[i] = es ? dsAc[b * 1024 + esc] : 0.f;
                dsv1[i] = es ? dsBc[b * 1024 + esc] : 0.f;
            }
        }

        // wave's A base: fragment chunks, 1KB hi + 1KB lo per kc, fully coalesced
        const unsigned short* aT = rc + ((size_t)m * 58 + kbase) * 1024 + lane * 8;

        f32x4 acc = {0.f, 0.f, 0.f, 0.f};
        short8 pah[6], pal[6];
        #pragma unroll
        for (int j = 0; j < 6; ++j) {
            pah[j] = *reinterpret_cast<const short8*>(aT + j * 1024);
            pal[j] = *reinterpret_cast<const short8*>(aT + j * 1024 + 512);
        }
        #pragma unroll
        for (int kc = 0; kc < 28; ++kc) {
            short8 cah = pah[kc % 6], cal = pal[kc % 6];
            if (kc < 22) {
                pah[kc % 6] = *reinterpret_cast<const short8*>(aT + (kc + 6) * 1024);
                pal[kc % 6] = *reinterpret_cast<const short8*>(aT + (kc + 6) * 1024 + 512);
            }
            int ka = kbase + kc;
            short8 bvh = *reinterpret_cast<const short8*>(Wh_s + (ka * 64 + lane) * 8);
            short8 bvl = *reinterpret_cast<const short8*>(Wl_s + (ka * 64 + lane) * 8);
            acc = __builtin_amdgcn_mfma_f32_16x16x32_bf16(cah, bvh, acc, 0, 0, 0);
            acc = __builtin_amdgcn_mfma_f32_16x16x32_bf16(cah, bvl, acc, 0, 0, 0);
            acc = __builtin_amdgcn_mfma_f32_16x16x32_bf16(cal, bvh, acc, 0, 0, 0);
        }
        if (kh) {
            #pragma unroll
            for (int c = 0; c < 2; ++c) {
                short8 bvh = *reinterpret_cast<const short8*>(Wh_s + ((56 + c) * 64 + lane) * 8);
                short8 bvl = *reinterpret_cast<const short8*>(Wl_s + ((56 + c) * 64 + lane) * 8);
                acc = __builtin_amdgcn_mfma_f32_16x16x32_bf16(xvh[c], bvh, acc, 0, 0, 0);
                acc = __builtin_amdgcn_mfma_f32_16x16x32_bf16(xvh[c], bvl, acc, 0, 0, 0);
                acc = __builtin_amdgcn_mfma_f32_16x16x32_bf16(xvl[c], bvh, acc, 0, 0, 0);
            }
            red_s[m * 64 + lane] = acc;
        }
        __syncthreads();

        if (!kh) {
            f32x4 o4 = red_s[m * 64 + lane];   // read scratch BEFORE reuse
            acc[0] += o4[0]; acc[1] += o4[1]; acc[2] += o4[2]; acc[3] += o4[3];
            char* wreg = scratch + m * 1024;   // this wave's private 1KB
            unsigned short* hiT = (unsigned short*)wreg;        // soma: [16row][16col]
            unsigned short* loT = hiT + 256;
            float*          fT  = (float*)wreg;                 // dend: [16row][16col]

            #pragma unroll
            for (int i = 0; i < 4; ++i) {
                float tot = acc[i] + bias_v;
                if (es) tot += dsv0[i] + dsv1[i];
                float hn = 0.8f * hreg[i] + 0.2f * tot + nsc * nz[i];
                hreg[i] = hn;
                float r = dend ? tanhf(hn) : fmaxf(hn, 0.f);
                int row = g * 4 + i;
                if (!dend) {
                    unsigned short hb = f2bf(r);
                    hiT[row * 16 + l15] = hb;
                    loT[row * 16 + l15] = f2bf(r - bf2f(hb));
                } else {
                    fT[row * 16 + l15] = r;
                }
                if (is_read) {
                    #pragma unroll
                    for (int o = 0; o < 10; ++o) {
                        float pp = r * wo[o];
                        pp += __shfl_xor(pp, 1);
                        pp += __shfl_xor(pp, 2);
                        pp += __shfl_xor(pp, 4);
                        pp += __shfl_xor(pp, 8);
                        int b = m * 16 + row;
                        if (l15 == 0)
                            __hip_atomic_store(&part[(size_t)t * 40960 + nt * 1280 + b * 10 + o],
                                               pp, __ATOMIC_RELAXED, __HIP_MEMORY_SCOPE_AGENT);
                    }
                }
            }
            // transpose-read + ONE coalesced 16B sc1 store per lane, fragment order
            if (!dend) {
                const unsigned short* sp = hiT + (lane >> 5) * 256
                                               + (lane & 15) * 16 + ((lane >> 4) & 1) * 8;
                unsigned short* dp = rn + ((size_t)m * 58 + (KB >> 1)) * 1024
                                        + (size_t)(KB & 1) * 256
                                        + (lane >> 5) * 512 + (lane & 31) * 8;
                st16_sc1(dp, *reinterpret_cast<const short8*>(sp));
            } else {
                int row = lane & 15, q = lane >> 4;
                int B = m * 16 + row;
                f32x4 v = *reinterpret_cast<f32x4*>(wreg + row * 64 + q * 16);
                float* base = (dbr ? dsBn : dsAn) + B * 1024 + dcol0;
                st16f_sc1((char*)base + q * 16, v);
            }
        }

        if (t != T_STEPS - 1) {
            const int e1 = t + 1;
            // prefetch pure inputs for t+1 before the barrier
            if (!kh) {
                const float* noise_nx = noise + (size_t)(t + 1) * B_SZ * N_TOT;
                #pragma unroll
                for (int i = 0; i < 4; ++i)
                    nz[i] = noise_nx[(size_t)(m * 16 + g * 4 + i) * N_TOT + n];
            } else {
                const unsigned short* xb = xF + ((size_t)((t + 1) * 8 + m) * 2) * 1024 + lane * 8;
                xvh[0] = *reinterpret_cast<const short8*>(xb);
                xvl[0] = *reinterpret_cast<const short8*>(xb + 512);
                xvh[1] = *reinterpret_cast<const short8*>(xb + 1024);
                xvl[1] = *reinterpret_cast<const short8*>(xb + 1536);
            }

            // ---- RMW-free sweep barrier (r12) + leader inv every 8 steps (r11) ----
            __syncthreads();    // drains all sc1 stores (vmcnt 0) before arrive
            if (tid == 0)
                __hip_atomic_store(&bar[nt * 16], e1,
                                   __ATOMIC_RELAXED, __HIP_MEMORY_SCOPE_AGENT);
            if (nt == ROOT_NT && wv == 0) {
                for (;;) {
                    bool ok = true;
                    #pragma unroll
                    for (int j = 0; j < 4; ++j) {
                        int idx = j * 64 + lane;
                        if (idx < NTILES) {
                            int v = __hip_atomic_load(&bar[idx * 16], __ATOMIC_RELAXED,
                                                      __HIP_MEMORY_SCOPE_AGENT);
                            ok = ok && (v >= e1);
                        }
                    }
                    if (__all(ok)) break;
                    __builtin_amdgcn_s_sleep(1);
                }
                #pragma unroll
                for (int j = 0; j < 4; ++j) {
                    int idx = j * 64 + lane;
                    if (idx < NTILES)
                        __hip_atomic_store(&bar[4096 + idx * 16], e1,
                                           __ATOMIC_RELAXED, __HIP_MEMORY_SCOPE_AGENT);
                }
            }
            if (tid == 0) {
                while (__hip_atomic_load(&bar[4096 + nt * 16], __ATOMIC_RELAXED,
                                         __HIP_MEMORY_SCOPE_AGENT) < e1)
                    __builtin_amdgcn_s_sleep(1);
                if ((t & (RING - 1)) == RING - 1) {
                    if (leader) {
                        __builtin_amdgcn_fence(__ATOMIC_ACQUIRE, "agent");  // 1 inv / 8 steps / XCD
                        __hip_atomic_store(&bar[8256 + xcc * 16], e1,
                                           __ATOMIC_RELAXED, __HIP_MEMORY_SCOPE_AGENT);
                    }
                    while (__hip_atomic_load(&bar[8256 + xcc * 16], __ATOMIC_RELAXED,
                                             __HIP_MEMORY_SCOPE_AGENT) < e1)
                        __builtin_amdgcn_s_sleep(1);
                }
                asm volatile("" ::: "memory");
            }
            __syncthreads();
        }
    }
}

extern "C" void kernel_launch(void* const* d_in, const int* in_sizes, int n_in,
                              void* d_out, int out_size, void* d_ws, size_t ws_size,
                              hipStream_t stream) {
    const float* x     = (const float*)d_in[0];
    const float* noise = (const float*)d_in[1];
    const float* w_rec = (const float*)d_in[2];
    const float* w_in  = (const float*)d_in[3];
    const float* w_out = (const float*)d_in[4];
    const float* bias  = (const float*)d_in[5];
    const float* h0    = (const float*)d_in[6];
    const float* mask  = (const float*)d_in[7];
    float* out = (float*)d_out;

    char* ws = (char*)d_ws;
    unsigned short* Wfh = (unsigned short*)(ws + 0);
    unsigned short* Wfl = (unsigned short*)(ws + 14254080);
    unsigned short* rFr = (unsigned short*)(ws + 28508160);   // 8 x 950272 B
    float* dsR = (float*)(ws + 36110336);                     // 8 x 1048576 B
    unsigned short* xF = (unsigned short*)(ws + 44498944);    // 6,553,600 B
    int*   bar  = (int*)(ws + 51052544);                      // 33,792 B
    float* part = (float*)(ws + 51086336);                    // 32,768,000 B

    hipLaunchKernelGGL(prep_w, dim3(15, 1856), dim3(256), 0, stream, w_rec, w_in, mask, Wfh, Wfl);
    hipLaunchKernelGGL(prep_xf, dim3(6400), dim3(256), 0, stream, x, xF);
    hipLaunchKernelGGL(init_state, dim3(15, B_SZ), dim3(256), 0, stream, h0, rFr, dsR);
    hipLaunchKernelGGL(zero_bar, dim3(1), dim3(1024), 0, stream, bar);

    void* params[] = {
        (void*)&Wfh, (void*)&Wfl, (void*)&rFr, (void*)&dsR, (void*)&xF,
        (void*)&noise, (void*)&bias, (void*)&w_out, (void*)&h0, (void*)&part, (void*)&bar
    };
    hipLaunchCooperativeKernel(rnn_persist, dim3(NTILES), dim3(1024), params, 0, stream);

    hipLaunchKernelGGL(reduce_out, dim3(T_STEPS), dim3(256), 0, stream, part, out);
}